// Round 10
// baseline (283.601 us; speedup 1.0000x reference)
//
#include <hip/hip_runtime.h>

#define INF_F 1e20f
#define B_ 16
#define Q_ 64
#define M_ 512
#define F_ 16
#define D_ 512

typedef __attribute__((ext_vector_type(8))) short short8v;
typedef __attribute__((ext_vector_type(4))) float f32x4;

static __device__ __forceinline__ float bits_f(unsigned u) { return __uint_as_float(u); }

// float4 -> hi bf16x4 (uint2) + residual-lo bf16x4 (uint2), truncation split
static __device__ __forceinline__ void split4(float4 v, uint2& H, uint2& L) {
    unsigned hx = __float_as_uint(v.x) & 0xffff0000u, hy = __float_as_uint(v.y) & 0xffff0000u;
    unsigned hz = __float_as_uint(v.z) & 0xffff0000u, hw = __float_as_uint(v.w) & 0xffff0000u;
    H.x = (hx >> 16) | hy;
    H.y = (hz >> 16) | hw;
    L.x = (__float_as_uint(v.x - bits_f(hx)) >> 16) | (__float_as_uint(v.y - bits_f(hy)) & 0xffff0000u);
    L.y = (__float_as_uint(v.z - bits_f(hz)) >> 16) | (__float_as_uint(v.w - bits_f(hw)) & 0xffff0000u);
}

static __device__ __forceinline__ short8v mk8(uint2 a, uint2 b) {
    union { uint4 u; short8v s; } r;
    r.u = make_uint4(a.x, a.y, b.x, b.y);
    return r.s;
}

// K0: q fragment-image: unit u = [b][kc][lg][row] -> 8 bf16 (hi & lo)
// containing query[b][row][kc*32 + lg*8 .. +7]
__global__ __launch_bounds__(256) void k_q_split(
    const float* __restrict__ q, short8v* __restrict__ qh, short8v* __restrict__ ql)
{
    int u = blockIdx.x * 256 + threadIdx.x;          // 0..65535
    int row = u & 63, lg = (u >> 6) & 3, kc = (u >> 8) & 15, b = u >> 12;
    const float4* q4 = (const float4*)q;
    size_t s = (size_t)(b * 64 + row) * 128 + kc * 8 + lg * 2;
    float4 v0 = q4[s], v1 = q4[s + 1];
    uint2 H0, L0, H1, L1;
    split4(v0, H0, L0);
    split4(v1, H1, L1);
    *(uint4*)&qh[u] = make_uint4(H0.x, H0.y, H1.x, H1.y);
    *(uint4*)&ql[u] = make_uint4(L0.x, L0.y, L1.x, L1.y);
}

// K1: role-split fused kernel, 768 blocks x 512 thr, bid%3==0 -> MFMA else streamer.
// MFMA block (k=bid/3): b=k>>4, 32 m; Q hi/lo resident in LDS in quarter-K chunks
// (q traffic 512MB -> 64MB); B-frags direct global->reg (vmcnt domain), Q reads
// LDS (lgkmcnt domain). Streamer block: both f-sums, 8 loads + 4 shuffles/chunk.
// Dispatch-order pairing: MFMA block k reads same in_mem rows as streamers 2k,2k+1.
__global__ __launch_bounds__(512, 3) void k_fused(
    const short8v* __restrict__ qhg, const short8v* __restrict__ qlg,
    const float* __restrict__ in_mem, const float* __restrict__ out_mem,
    const float* __restrict__ ctx_mask, const float* __restrict__ query_mask,
    float* __restrict__ att_qm, float* __restrict__ in_mem_base,
    float* __restrict__ out_mem_sum)
{
    __shared__ short8v QH[1024];   // 16 KB: quarter-K q-image (hi)
    __shared__ short8v QL[1024];   // 16 KB: (lo)

    const int bid = blockIdx.x;
    const int t   = threadIdx.x;

    if (bid % 3 == 0) {
        // ---------------- Q-resident MFMA path ----------------
        const int k  = bid / 3;            // 0..255
        const int b  = k >> 4;
        const int m0 = (k & 15) * 32;
        const int w  = t >> 6;             // wave 0..7 -> m = m0 + w*4 ..+3
        const int lane = t & 63;
        const int lr = lane & 15;          // B fragment row (= f)
        const int lg = lane >> 4;          // k-granule
        const float4* in4 = (const float4*)in_mem;
        const int qgb = b * 4096;          // global q-image base (units)

        #pragma unroll
        for (int p = 0; p < 2; ++p) {      // m-tile pair: tiles {w*4+2p, w*4+2p+1}
            f32x4 acc[2][4];
            #pragma unroll
            for (int i = 0; i < 2; ++i)
                #pragma unroll
                for (int j = 0; j < 4; ++j) acc[i][j] = (f32x4){0, 0, 0, 0};

            const size_t rb0 = ((size_t)((b * M_ + m0 + w * 4 + 2 * p) * F_) + lr) * 128 + lg * 2;
            const size_t rb1 = rb0 + (size_t)F_ * 128;
            float4 s0[4], s1[4];

            #pragma unroll
            for (int qp = 0; qp < 4; ++qp) {   // K-quarter: kc = qp*4 + kq
                __syncthreads();               // protect Q LDS from prior readers
                {   // issue B step-0 loads first (latency overlaps Q fill)
                    const size_t o = (size_t)(qp * 4) * 8;
                    s0[0] = in4[rb0 + o]; s0[1] = in4[rb0 + o + 1];
                    s0[2] = in4[rb1 + o]; s0[3] = in4[rb1 + o + 1];
                }
                QH[t]       = qhg[qgb + qp * 1024 + t];
                QH[t + 512] = qhg[qgb + qp * 1024 + t + 512];
                QL[t]       = qlg[qgb + qp * 1024 + t];
                QL[t + 512] = qlg[qgb + qp * 1024 + t + 512];
                __syncthreads();               // Q quarter visible (drains vmem too)

                #pragma unroll
                for (int kq = 0; kq < 4; ++kq) {
                    float4* sc = (kq & 1) ? s1 : s0;
                    float4* sn = (kq & 1) ? s0 : s1;
                    if (kq < 3) {              // issue next step (stays in flight)
                        const size_t o = (size_t)(qp * 4 + kq + 1) * 8;
                        sn[0] = in4[rb0 + o]; sn[1] = in4[rb0 + o + 1];
                        sn[2] = in4[rb1 + o]; sn[3] = in4[rb1 + o + 1];
                    }
                    uint2 H0, L0, H1, L1;
                    split4(sc[0], H0, L0); split4(sc[1], H1, L1);
                    short8v bh0 = mk8(H0, H1), bl0 = mk8(L0, L1);
                    split4(sc[2], H0, L0); split4(sc[3], H1, L1);
                    short8v bh1 = mk8(H0, H1), bl1 = mk8(L0, L1);
                    const int qu = kq * 256 + lg * 64 + lr;
                    __builtin_amdgcn_s_setprio(1);
                    #pragma unroll
                    for (int tq = 0; tq < 4; ++tq) {
                        short8v ah = QH[qu + tq * 16];
                        short8v al = QL[qu + tq * 16];
                        acc[0][tq] = __builtin_amdgcn_mfma_f32_16x16x32_bf16(ah, bh0, acc[0][tq], 0, 0, 0);
                        acc[0][tq] = __builtin_amdgcn_mfma_f32_16x16x32_bf16(ah, bl0, acc[0][tq], 0, 0, 0);
                        acc[0][tq] = __builtin_amdgcn_mfma_f32_16x16x32_bf16(al, bh0, acc[0][tq], 0, 0, 0);
                        acc[1][tq] = __builtin_amdgcn_mfma_f32_16x16x32_bf16(ah, bh1, acc[1][tq], 0, 0, 0);
                        acc[1][tq] = __builtin_amdgcn_mfma_f32_16x16x32_bf16(ah, bl1, acc[1][tq], 0, 0, 0);
                        acc[1][tq] = __builtin_amdgcn_mfma_f32_16x16x32_bf16(al, bh1, acc[1][tq], 0, 0, 0);
                    }
                    __builtin_amdgcn_s_setprio(0);
                }
            }

            // epilogue for pair p: masks + max over f (16-lane groups) -> att_qm
            #pragma unroll
            for (int tm = 0; tm < 2; ++tm) {
                int m = m0 + w * 4 + 2 * p + tm;
                float cmv = ctx_mask[((size_t)b * M_ + m) * F_ + lr];
                #pragma unroll
                for (int tq = 0; tq < 4; ++tq) {
                    #pragma unroll
                    for (int rg = 0; rg < 4; ++rg) {
                        int q = tq * 16 + lg * 4 + rg;
                        float qmv = query_mask[b * Q_ + q];
                        float v = acc[tm][tq][rg];
                        v = cmv * v - (1.0f - cmv) * INF_F;
                        v = qmv * v - (1.0f - qmv) * INF_F;
                        #pragma unroll
                        for (int sh = 1; sh < 16; sh <<= 1) v = fmaxf(v, __shfl_xor(v, sh, 64));
                        if (lr == 0)
                            att_qm[((size_t)b * Q_ + q) * M_ + m] = v;
                    }
                }
            }
        }
        return;
    }

    // ---------------- streamer path (both f-sums) ----------------
    const int s    = bid - bid / 3 - 1;      // 0..511
    const int b    = s >> 5;
    const int m0   = (s & 31) * 16;
    const int msel = t >> 5;                 // m = m0 + msel (16 m)
    const int r5   = t & 31;
    const int c    = r5 >> 2;                // float4 col 0..7
    const int half = (r5 >> 1) & 1;          // f-half
    const int strm = r5 & 1;                 // 0 = in (weighted), 1 = out (plain)

    float wj[8];
    if (strm == 0) {
        const float* cm = ctx_mask + ((size_t)b * M_ + m0 + msel) * F_;
        float wv[16]; float mx = -INF_F;
        #pragma unroll
        for (int f = 0; f < 16; ++f) {
            float cv = cm[f];
            float v = cv - (1.0f - cv) * INF_F;
            wv[f] = v; mx = fmaxf(mx, v);
        }
        float sum = 0.f;
        #pragma unroll
        for (int f = 0; f < 16; ++f) { wv[f] = __expf(wv[f] - mx); sum += wv[f]; }
        float inv = 1.0f / sum;
        #pragma unroll
        for (int j = 0; j < 8; ++j) wj[j] = wv[half * 8 + j] * inv;
    } else {
        #pragma unroll
        for (int j = 0; j < 8; ++j) wj[j] = 1.0f;
    }

    const float4* fsrc = strm ? (const float4*)out_mem : (const float4*)in_mem;
    float4* fdst       = strm ? (float4*)out_mem_sum : (float4*)in_mem_base;
    const size_t fbase = ((size_t)((b * M_ + m0 + msel) * F_ + half * 8)) * 128 + c;
    const size_t obase = (size_t)(b * M_ + m0 + msel) * 128 + c;

    float4 fa[8], fb[8];
    #pragma unroll
    for (int j = 0; j < 8; ++j) fa[j] = fsrc[fbase + (size_t)j * 128];

#define FBODY(kc_, cur, nxt) do {                                              \
        if ((kc_) < 15) {                                                      \
            _Pragma("unroll")                                                  \
            for (int j = 0; j < 8; ++j)                                        \
                nxt[j] = fsrc[fbase + (size_t)j * 128 + ((kc_) + 1) * 8];      \
        }                                                                      \
        float4 s4 = make_float4(0, 0, 0, 0);                                   \
        _Pragma("unroll")                                                      \
        for (int j = 0; j < 8; ++j) {                                          \
            s4.x += wj[j] * cur[j].x; s4.y += wj[j] * cur[j].y;                \
            s4.z += wj[j] * cur[j].z; s4.w += wj[j] * cur[j].w;                \
        }                                                                      \
        s4.x += __shfl_xor(s4.x, 2, 64); s4.y += __shfl_xor(s4.y, 2, 64);      \
        s4.z += __shfl_xor(s4.z, 2, 64); s4.w += __shfl_xor(s4.w, 2, 64);      \
        if (half == 0) fdst[obase + (kc_) * 8] = s4;                           \
    } while (0)

    #pragma unroll
    for (int it = 0; it < 8; ++it) {
        FBODY(2 * it, fa, fb);
        FBODY(2 * it + 1, fb, fa);
    }
#undef FBODY
}

// K2: softmax over M (in-block) + new_query = query + probs @ out_mem_sum; 8 q/block
__global__ __launch_bounds__(128) void k_new_query(
    const float* __restrict__ att, const float* __restrict__ query,
    const float* __restrict__ out_sum, float* __restrict__ new_q)
{
    __shared__ float P[8][512];
    int bid = blockIdx.x;
    int b = bid & 15, qc = bid >> 4;
    int t = threadIdx.x;
    {
        int qi = t >> 4, l16 = t & 15;
        const float* row = att + ((size_t)b * Q_ + qc * 8 + qi) * M_;
        float vals[32]; float mx = -INF_F;
        #pragma unroll
        for (int i = 0; i < 32; ++i) { vals[i] = row[l16 + i * 16]; mx = fmaxf(mx, vals[i]); }
        #pragma unroll
        for (int s = 1; s < 16; s <<= 1) mx = fmaxf(mx, __shfl_xor(mx, s, 64));
        float sm = 0.f;
        #pragma unroll
        for (int i = 0; i < 32; ++i) { vals[i] = __expf(vals[i] - mx); sm += vals[i]; }
        #pragma unroll
        for (int s = 1; s < 16; s <<= 1) sm += __shfl_xor(sm, s, 64);
        float inv = 1.0f / sm;
        #pragma unroll
        for (int i = 0; i < 32; ++i) P[qi][l16 + i * 16] = vals[i] * inv;
    }
    __syncthreads();
    int c = t;
    const float4* o4 = (const float4*)out_sum + (size_t)b * M_ * 128 + c;
    const float4* q4 = (const float4*)query + ((size_t)b * Q_ + qc * 8) * 128 + c;
    float4 acc[8];
    #pragma unroll
    for (int qi = 0; qi < 8; ++qi) acc[qi] = q4[(size_t)qi * 128];
    for (int mm = 0; mm < M_; mm += 4) {
        float4 o0 = o4[(size_t)(mm + 0) * 128];
        float4 o1 = o4[(size_t)(mm + 1) * 128];
        float4 o2 = o4[(size_t)(mm + 2) * 128];
        float4 o3 = o4[(size_t)(mm + 3) * 128];
        #pragma unroll
        for (int qi = 0; qi < 8; ++qi) {
            float4 p = *(const float4*)&P[qi][mm];
            acc[qi].x += p.x * o0.x + p.y * o1.x + p.z * o2.x + p.w * o3.x;
            acc[qi].y += p.x * o0.y + p.y * o1.y + p.z * o2.y + p.w * o3.y;
            acc[qi].z += p.x * o0.z + p.y * o1.z + p.z * o2.z + p.w * o3.z;
            acc[qi].w += p.x * o0.w + p.y * o1.w + p.z * o2.w + p.w * o3.w;
        }
    }
    float4* n4 = (float4*)new_q + ((size_t)b * Q_ + qc * 8) * 128 + c;
    #pragma unroll
    for (int qi = 0; qi < 8; ++qi) n4[(size_t)qi * 128] = acc[qi];
}

// K3: softmax over Q (in-block) + in_mem += p2 @ new_query; 8 m/block
__global__ __launch_bounds__(128) void k_in_mem(
    const float* __restrict__ att, const float* __restrict__ new_q,
    float* __restrict__ in_mem_io)
{
    __shared__ float P[8][64];
    int bid = blockIdx.x;
    int b = bid & 15, mc = bid >> 4;
    int m0 = mc * 8;
    int t = threadIdx.x;
    {
        int mi = t >> 4, l16 = t & 15;
        float v[4]; float mx = -INF_F;
        #pragma unroll
        for (int i = 0; i < 4; ++i) {
            v[i] = att[((size_t)b * Q_ + l16 + i * 16) * M_ + m0 + mi];
            mx = fmaxf(mx, v[i]);
        }
        #pragma unroll
        for (int s = 1; s < 16; s <<= 1) mx = fmaxf(mx, __shfl_xor(mx, s, 64));
        float sm = 0.f;
        #pragma unroll
        for (int i = 0; i < 4; ++i) { v[i] = __expf(v[i] - mx); sm += v[i]; }
        #pragma unroll
        for (int s = 1; s < 16; s <<= 1) sm += __shfl_xor(sm, s, 64);
        float inv = 1.0f / sm;
        #pragma unroll
        for (int i = 0; i < 4; ++i) P[mi][l16 + i * 16] = v[i] * inv;
    }
    __syncthreads();
    int c = t;
    float4* io = (float4*)in_mem_io + ((size_t)b * M_ + m0) * 128 + c;
    const float4* n4 = (const float4*)new_q + (size_t)b * Q_ * 128 + c;
    float4 acc[8];
    #pragma unroll
    for (int mi = 0; mi < 8; ++mi) acc[mi] = io[(size_t)mi * 128];
    for (int q = 0; q < Q_; q += 4) {
        float4 n0 = n4[(size_t)(q + 0) * 128];
        float4 n1 = n4[(size_t)(q + 1) * 128];
        float4 n2 = n4[(size_t)(q + 2) * 128];
        float4 n3 = n4[(size_t)(q + 3) * 128];
        #pragma unroll
        for (int mi = 0; mi < 8; ++mi) {
            float4 p = *(const float4*)&P[mi][q];
            acc[mi].x += p.x * n0.x + p.y * n1.x + p.z * n2.x + p.w * n3.x;
            acc[mi].y += p.x * n0.y + p.y * n1.y + p.z * n2.y + p.w * n3.y;
            acc[mi].z += p.x * n0.z + p.y * n1.z + p.z * n2.z + p.w * n3.z;
            acc[mi].w += p.x * n0.w + p.y * n1.w + p.z * n2.w + p.w * n3.w;
        }
    }
    #pragma unroll
    for (int mi = 0; mi < 8; ++mi) io[(size_t)mi * 128] = acc[mi];
}

extern "C" void kernel_launch(void* const* d_in, const int* in_sizes, int n_in,
                              void* d_out, int out_size, void* d_ws, size_t ws_size,
                              hipStream_t stream)
{
    const float* query      = (const float*)d_in[0];
    const float* in_mem     = (const float*)d_in[1];
    const float* out_mem    = (const float*)d_in[2];
    const float* ctx_mask   = (const float*)d_in[3];
    const float* query_mask = (const float*)d_in[4];

    float* out = (float*)d_out;
    float* new_q      = out;                             // B*Q*D
    float* in_mem_out = out + (size_t)B_*Q_*D_;          // B*M*D
    float* out_mem_o  = in_mem_out + (size_t)B_*M_*D_;   // B*M*D

    float* ws       = (float*)d_ws;
    float* att_qm   = ws;                                // B*Q*M floats (2 MB)
    short8v* qh     = (short8v*)(ws + (size_t)B_*Q_*M_); // 65536 units (1 MB)
    short8v* ql     = qh + 65536;                        // 1 MB

    hipLaunchKernelGGL(k_q_split, dim3(256), dim3(256), 0, stream, query, qh, ql);
    hipLaunchKernelGGL(k_fused, dim3(768), dim3(512), 0, stream,
                       qh, ql, in_mem, out_mem, ctx_mask, query_mask,
                       att_qm, in_mem_out, out_mem_o);
    hipLaunchKernelGGL(k_new_query, dim3(8 * B_), dim3(128), 0, stream,
                       att_qm, query, out_mem_o, new_q);
    hipLaunchKernelGGL(k_in_mem, dim3(64 * B_), dim3(128), 0, stream,
                       att_qm, new_q, in_mem_out);
}

// Round 11
// 280.876 us; speedup vs baseline: 1.0097x; 1.0097x over previous
//
#include <hip/hip_runtime.h>

#define INF_F 1e20f
#define B_ 16
#define Q_ 64
#define M_ 512
#define F_ 16
#define D_ 512

typedef __attribute__((ext_vector_type(8))) short short8v;
typedef __attribute__((ext_vector_type(4))) float f32x4;

static __device__ __forceinline__ float bits_f(unsigned u) { return __uint_as_float(u); }

// float4 -> hi bf16x4 (uint2) + residual-lo bf16x4 (uint2), truncation split
static __device__ __forceinline__ void split4(float4 v, uint2& H, uint2& L) {
    unsigned hx = __float_as_uint(v.x) & 0xffff0000u, hy = __float_as_uint(v.y) & 0xffff0000u;
    unsigned hz = __float_as_uint(v.z) & 0xffff0000u, hw = __float_as_uint(v.w) & 0xffff0000u;
    H.x = (hx >> 16) | hy;
    H.y = (hz >> 16) | hw;
    L.x = (__float_as_uint(v.x - bits_f(hx)) >> 16) | (__float_as_uint(v.y - bits_f(hy)) & 0xffff0000u);
    L.y = (__float_as_uint(v.z - bits_f(hz)) >> 16) | (__float_as_uint(v.w - bits_f(hw)) & 0xffff0000u);
}

// K0: q fragment-image: unit u = [b][kc][lg][row] -> 8 bf16 (hi & lo)
// containing query[b][row][kc*32 + lg*8 .. +7]
__global__ __launch_bounds__(256) void k_q_split(
    const float* __restrict__ q, short8v* __restrict__ qh, short8v* __restrict__ ql)
{
    int u = blockIdx.x * 256 + threadIdx.x;          // 0..65535
    int row = u & 63, lg = (u >> 6) & 3, kc = (u >> 8) & 15, b = u >> 12;
    const float4* q4 = (const float4*)q;
    size_t s = (size_t)(b * 64 + row) * 128 + kc * 8 + lg * 2;
    float4 v0 = q4[s], v1 = q4[s + 1];
    uint2 H0, L0, H1, L1;
    split4(v0, H0, L0);
    split4(v1, H1, L1);
    *(uint4*)&qh[u] = make_uint4(H0.x, H0.y, H1.x, H1.y);
    *(uint4*)&ql[u] = make_uint4(L0.x, L0.y, L1.x, L1.y);
}

// K1: roles by bid&1. mg = bid>>1: b = mg>>4, m0 = (mg&15)*32 (32 m per pair).
//  even: MFMA block, 4 independent waves; wave owns 8 m x 64 q x full K.
//        Lane (mm=lane>>3, c=lane&7) streams all 16 f of its m (in_mem read ONCE):
//        weighted f-sum = in-lane FMAs + direct store (no shuffles); hi/lo bf16
//        conv -> wave-private LDS (no barriers: DS wave-ordered, R9-proven);
//        MFMA reads frags back. FIFO-monotone issue -> counted vmcnt only.
//  odd:  streamer: plain f-sum of out_memory for the same 32 m (only out read).
__global__ __launch_bounds__(256, 1) void k_att(
    const short8v* __restrict__ qhg, const short8v* __restrict__ qlg,
    const float* __restrict__ in_mem, const float* __restrict__ out_mem,
    const float* __restrict__ ctx_mask, const float* __restrict__ query_mask,
    float* __restrict__ att_qm, float* __restrict__ in_mem_base,
    float* __restrict__ out_mem_sum)
{
    __shared__ __align__(16) short HB[4][4096];   // 32 KB: per-wave 128 rows x 32 bf16
    __shared__ __align__(16) short LB[4][4096];   // 32 KB

    const int bid = blockIdx.x;
    const int mg  = bid >> 1;
    const int b   = mg >> 4;
    const int m0  = (mg & 15) * 32;
    const int t   = threadIdx.x;

    if (bid & 1) {
        // ---------------- out-sum streamer: 32 m ----------------
        const int m = m0 + (t >> 3), c = t & 7;
        const float4* src = (const float4*)out_mem + (size_t)((b * M_ + m) * F_) * 128;
        float4* dst = (float4*)out_mem_sum + (size_t)(b * M_ + m) * 128;
        #pragma unroll
        for (int j = 0; j < 16; ++j) {
            int col = c + j * 8;
            float4 s = make_float4(0, 0, 0, 0);
            #pragma unroll
            for (int f = 0; f < 16; ++f) {
                float4 v = src[f * 128 + col];
                s.x += v.x; s.y += v.y; s.z += v.z; s.w += v.w;
            }
            dst[col] = s;
        }
        return;
    }

    // ---------------- MFMA path ----------------
    const int w = t >> 6, lane = t & 63;
    const int lr = lane & 15, lg = lane >> 4;     // fragment row (=f), k-granule
    const int mm = lane >> 3, c = lane & 7;       // staging: my m, float4 col
    const int mw0 = m0 + w * 8;                   // wave's 8 m
    short* Hb = HB[w];
    short* Lb = LB[w];
    const int wg = (((c >> 1) ^ (mm & 3)) << 3) + ((c & 1) << 2);   // write swz (shorts)

    // softmax-over-f weights for my m (all 16 f in-lane)
    float wj[16];
    {
        const float* cm = ctx_mask + (size_t)(b * M_ + mw0 + mm) * F_;
        float wv[16]; float mx = -INF_F;
        #pragma unroll
        for (int f = 0; f < 16; ++f) {
            float cv = cm[f];
            float v = cv - (1.0f - cv) * INF_F;
            wv[f] = v; mx = fmaxf(mx, v);
        }
        float s = 0.f;
        #pragma unroll
        for (int f = 0; f < 16; ++f) { wv[f] = __expf(wv[f] - mx); s += wv[f]; }
        float inv = 1.0f / s;
        #pragma unroll
        for (int f = 0; f < 16; ++f) wj[f] = wv[f] * inv;
    }

    const float4* in4 = (const float4*)in_mem;
    const size_t gbase = (size_t)((b * M_ + mw0 + mm) * F_) * 128 + c;  // + f*128 + kc*8
    const size_t obase = (size_t)(b * M_ + mw0 + mm) * 128 + c;         // + kc*8
    const int qb0 = b * 4096 + lg * 64 + lr;                            // + kc*256 + tq*16

    f32x4 acc[8][4];
    #pragma unroll
    for (int i = 0; i < 8; ++i)
        #pragma unroll
        for (int j = 0; j < 4; ++j) acc[i][j] = (f32x4){0, 0, 0, 0};

    float4 sA[8], sB[8];
    short8v qf[8];

    // prologue (FIFO: sA, sB, qf)
    #pragma unroll
    for (int i = 0; i < 8; ++i) sA[i] = in4[gbase + (size_t)i * 128];
    #pragma unroll
    for (int i = 0; i < 8; ++i) sB[i] = in4[gbase + (size_t)(8 + i) * 128];
    #pragma unroll
    for (int tq = 0; tq < 4; ++tq) { qf[2*tq] = qhg[qb0 + tq*16]; qf[2*tq+1] = qlg[qb0 + tq*16]; }

    #pragma unroll
    for (int kc = 0; kc < 16; ++kc) {
        float4 fs = make_float4(0, 0, 0, 0);
        // consume sA (f 0..7): conv -> LDS + weighted partial
        #pragma unroll
        for (int i = 0; i < 8; ++i) {
            float4 v = sA[i];
            uint2 H, L; split4(v, H, L);
            int woff = (mm * 16 + i) * 32 + wg;
            *(uint2*)&Hb[woff] = H;
            *(uint2*)&Lb[woff] = L;
            fs.x += wj[i]*v.x; fs.y += wj[i]*v.y; fs.z += wj[i]*v.z; fs.w += wj[i]*v.w;
        }
        if (kc < 15) {
            #pragma unroll
            for (int i = 0; i < 8; ++i) sA[i] = in4[gbase + (size_t)i * 128 + (kc + 1) * 8];
        }
        // consume sB (f 8..15)
        #pragma unroll
        for (int i = 0; i < 8; ++i) {
            float4 v = sB[i];
            uint2 H, L; split4(v, H, L);
            int woff = (mm * 16 + 8 + i) * 32 + wg;
            *(uint2*)&Hb[woff] = H;
            *(uint2*)&Lb[woff] = L;
            float wf = wj[8 + i];
            fs.x += wf*v.x; fs.y += wf*v.y; fs.z += wf*v.z; fs.w += wf*v.w;
        }
        if (kc < 15) {
            #pragma unroll
            for (int i = 0; i < 8; ++i) sB[i] = in4[gbase + (size_t)(8 + i) * 128 + (kc + 1) * 8];
        }
        // weighted in-sum: complete for (my m, this d-chunk col) -> direct store
        ((float4*)in_mem_base)[obase + kc * 8] = fs;

        // MFMA from wave-private LDS (DS wave-ordered; no barrier)
        __builtin_amdgcn_s_setprio(1);
        #pragma unroll
        for (int tm = 0; tm < 8; ++tm) {
            int roff = (tm * 16 + lr) * 32 + ((lg ^ (tm & 3)) << 3);
            short8v bh = *(const short8v*)&Hb[roff];
            short8v bl = *(const short8v*)&Lb[roff];
            #pragma unroll
            for (int tq = 0; tq < 4; ++tq) {
                short8v ah = qf[2*tq], al = qf[2*tq+1];
                acc[tm][tq] = __builtin_amdgcn_mfma_f32_16x16x32_bf16(ah, bh, acc[tm][tq], 0, 0, 0);
                acc[tm][tq] = __builtin_amdgcn_mfma_f32_16x16x32_bf16(ah, bl, acc[tm][tq], 0, 0, 0);
                acc[tm][tq] = __builtin_amdgcn_mfma_f32_16x16x32_bf16(al, bh, acc[tm][tq], 0, 0, 0);
            }
        }
        __builtin_amdgcn_s_setprio(0);
        if (kc < 15) {
            int qb = qb0 + (kc + 1) * 256;
            #pragma unroll
            for (int tq = 0; tq < 4; ++tq) { qf[2*tq] = qhg[qb + tq*16]; qf[2*tq+1] = qlg[qb + tq*16]; }
        }
    }

    // masks + max over f (16-lane groups) -> att_qm
    #pragma unroll
    for (int tm = 0; tm < 8; ++tm) {
        int m = mw0 + tm;
        float cmv = ctx_mask[(size_t)(b * M_ + m) * F_ + lr];
        #pragma unroll
        for (int tq = 0; tq < 4; ++tq) {
            #pragma unroll
            for (int rg = 0; rg < 4; ++rg) {
                int q = tq * 16 + lg * 4 + rg;
                float qmv = query_mask[b * Q_ + q];
                float v = acc[tm][tq][rg];
                v = cmv * v - (1.0f - cmv) * INF_F;
                v = qmv * v - (1.0f - qmv) * INF_F;
                #pragma unroll
                for (int sh = 1; sh < 16; sh <<= 1) v = fmaxf(v, __shfl_xor(v, sh, 64));
                if (lr == 0)
                    att_qm[(size_t)(b * Q_ + q) * M_ + m] = v;
            }
        }
    }
}

// K2: softmax over M (in-block) + new_query = query + probs @ out_mem_sum; 16 q/block
__global__ __launch_bounds__(256) void k_new_query(
    const float* __restrict__ att, const float* __restrict__ query,
    const float* __restrict__ out_sum, float* __restrict__ new_q)
{
    __shared__ float P[16][512];     // 32 KB
    int bid = blockIdx.x;
    int b = bid >> 2, qc = bid & 3;
    int t = threadIdx.x;
    {
        int qi = t >> 4, l16 = t & 15;
        const float* row = att + (size_t)(b * Q_ + qc * 16 + qi) * M_;
        float vals[32]; float mx = -INF_F;
        #pragma unroll
        for (int i = 0; i < 32; ++i) { vals[i] = row[l16 + i * 16]; mx = fmaxf(mx, vals[i]); }
        #pragma unroll
        for (int s = 1; s < 16; s <<= 1) mx = fmaxf(mx, __shfl_xor(mx, s, 64));
        float sm = 0.f;
        #pragma unroll
        for (int i = 0; i < 32; ++i) { vals[i] = __expf(vals[i] - mx); sm += vals[i]; }
        #pragma unroll
        for (int s = 1; s < 16; s <<= 1) sm += __shfl_xor(sm, s, 64);
        float inv = 1.0f / sm;
        #pragma unroll
        for (int i = 0; i < 32; ++i) P[qi][l16 + i * 16] = vals[i] * inv;
    }
    __syncthreads();
    int cph = t >> 7, cc = t & 127;
    const float4* o4 = (const float4*)out_sum + (size_t)b * M_ * 128 + cc;
    const float4* q4 = (const float4*)query + (size_t)(b * Q_ + qc * 16 + cph * 8) * 128 + cc;
    float4 acc[8];
    #pragma unroll
    for (int qi = 0; qi < 8; ++qi) acc[qi] = q4[(size_t)qi * 128];
    for (int mmv = 0; mmv < M_; mmv += 4) {
        float4 o0 = o4[(size_t)(mmv + 0) * 128];
        float4 o1 = o4[(size_t)(mmv + 1) * 128];
        float4 o2 = o4[(size_t)(mmv + 2) * 128];
        float4 o3 = o4[(size_t)(mmv + 3) * 128];
        #pragma unroll
        for (int qi = 0; qi < 8; ++qi) {
            float4 p = *(const float4*)&P[cph * 8 + qi][mmv];
            acc[qi].x += p.x * o0.x + p.y * o1.x + p.z * o2.x + p.w * o3.x;
            acc[qi].y += p.x * o0.y + p.y * o1.y + p.z * o2.y + p.w * o3.y;
            acc[qi].z += p.x * o0.z + p.y * o1.z + p.z * o2.z + p.w * o3.z;
            acc[qi].w += p.x * o0.w + p.y * o1.w + p.z * o2.w + p.w * o3.w;
        }
    }
    float4* n4 = (float4*)new_q + (size_t)(b * Q_ + qc * 16 + cph * 8) * 128 + cc;
    #pragma unroll
    for (int qi = 0; qi < 8; ++qi) n4[(size_t)qi * 128] = acc[qi];
}

// K3: softmax over Q (in-block) + in_mem += p2 @ new_query; 16 m/block
__global__ __launch_bounds__(128) void k_in_mem(
    const float* __restrict__ att, const float* __restrict__ new_q,
    float* __restrict__ in_mem_io)
{
    __shared__ float P[16][64];      // 4 KB
    int bid = blockIdx.x;
    int b = bid & 15, mc = bid >> 4;     // mc 0..31
    int m0 = mc * 16;
    int t = threadIdx.x;
    {
        int mi = t >> 3, l8 = t & 7;
        float v[8]; float mx = -INF_F;
        #pragma unroll
        for (int i = 0; i < 8; ++i) {
            v[i] = att[(size_t)(b * Q_ + l8 + i * 8) * M_ + m0 + mi];
            mx = fmaxf(mx, v[i]);
        }
        #pragma unroll
        for (int s = 1; s < 8; s <<= 1) mx = fmaxf(mx, __shfl_xor(mx, s, 64));
        float sm = 0.f;
        #pragma unroll
        for (int i = 0; i < 8; ++i) { v[i] = __expf(v[i] - mx); sm += v[i]; }
        #pragma unroll
        for (int s = 1; s < 8; s <<= 1) sm += __shfl_xor(sm, s, 64);
        float inv = 1.0f / sm;
        #pragma unroll
        for (int i = 0; i < 8; ++i) P[mi][l8 + i * 8] = v[i] * inv;
    }
    __syncthreads();
    int cc = t;
    float4* io = (float4*)in_mem_io + (size_t)(b * M_ + m0) * 128 + cc;
    const float4* n4 = (const float4*)new_q + (size_t)b * Q_ * 128 + cc;
    float4 acc[16];
    #pragma unroll
    for (int mi = 0; mi < 16; ++mi) acc[mi] = io[(size_t)mi * 128];
    for (int q = 0; q < Q_; q += 2) {
        float4 n0 = n4[(size_t)(q + 0) * 128];
        float4 n1 = n4[(size_t)(q + 1) * 128];
        #pragma unroll
        for (int mi = 0; mi < 16; ++mi) {
            float4 p2 = *(const float4*)&P[mi][q & 60];   // aligned float4 window
            float p0 = ((q & 2) == 0) ? p2.x : p2.z;
            float p1 = ((q & 2) == 0) ? p2.y : p2.w;
            acc[mi].x += p0 * n0.x + p1 * n1.x;
            acc[mi].y += p0 * n0.y + p1 * n1.y;
            acc[mi].z += p0 * n0.z + p1 * n1.z;
            acc[mi].w += p0 * n0.w + p1 * n1.w;
        }
    }
    #pragma unroll
    for (int mi = 0; mi < 16; ++mi) io[(size_t)mi * 128] = acc[mi];
}

extern "C" void kernel_launch(void* const* d_in, const int* in_sizes, int n_in,
                              void* d_out, int out_size, void* d_ws, size_t ws_size,
                              hipStream_t stream)
{
    const float* query      = (const float*)d_in[0];
    const float* in_mem     = (const float*)d_in[1];
    const float* out_mem    = (const float*)d_in[2];
    const float* ctx_mask   = (const float*)d_in[3];
    const float* query_mask = (const float*)d_in[4];

    float* out = (float*)d_out;
    float* new_q      = out;                             // B*Q*D
    float* in_mem_out = out + (size_t)B_*Q_*D_;          // B*M*D
    float* out_mem_o  = in_mem_out + (size_t)B_*M_*D_;   // B*M*D

    float* ws       = (float*)d_ws;
    float* att_qm   = ws;                                // B*Q*M floats (2 MB)
    short8v* qh     = (short8v*)(ws + (size_t)B_*Q_*M_); // 65536 units (1 MB)
    short8v* ql     = qh + 65536;                        // 1 MB

    hipLaunchKernelGGL(k_q_split, dim3(256), dim3(256), 0, stream, query, qh, ql);
    hipLaunchKernelGGL(k_att, dim3(512), dim3(256), 0, stream,
                       qh, ql, in_mem, out_mem, ctx_mask, query_mask,
                       att_qm, in_mem_out, out_mem_o);
    hipLaunchKernelGGL(k_new_query, dim3(64), dim3(256), 0, stream,
                       att_qm, query, out_mem_o, new_q);
    hipLaunchKernelGGL(k_in_mem, dim3(32 * B_), dim3(128), 0, stream,
                       att_qm, new_q, in_mem_out);
}